// Round 5
// baseline (312.488 us; speedup 1.0000x reference)
//
#include <hip/hip_runtime.h>

#define NN 50000
#define NE 600000
#define F_IN 57
#define HID 128
#define NEG 0.2f
#define NB_SCAN ((NN + 255) / 256)

#define GIN_NODES 64
#define NB_GIN ((NN + GIN_NODES - 1) / GIN_NODES)
#define XST 68

#define TN 32                  // nodes per fused sage+dense block
#define NB_DENSE ((NN + TN - 1) / TN)
#define AST 132                // activation row stride (floats)

__device__ __forceinline__ float leaky(float v) { return v >= 0.f ? v : NEG * v; }

// ---------------- K1: tiled  h = x @ W_gat ; hs = h.a_src ; hd = h.a_dst ----------------
__global__ __launch_bounds__(256) void k_gat_in(
    const float* __restrict__ x, const float* __restrict__ Wg,
    const float* __restrict__ a_s, const float* __restrict__ a_d,
    float* __restrict__ h, float* __restrict__ hs, float* __restrict__ hd) {
    __shared__ float WgS[F_IN * HID];
    __shared__ float xsT[F_IN][XST];
    int tid = threadIdx.x;
    int node0 = blockIdx.x * GIN_NODES;
    {
        const float4* g = (const float4*)Wg;
        float4* s = (float4*)WgS;
        for (int i = tid; i < F_IN * HID / 4; i += 256) s[i] = g[i];
    }
    for (int i = tid; i < GIN_NODES * F_IN; i += 256) {
        int n = i / F_IN;
        int k = i - n * F_IN;
        int gn = node0 + n;
        if (gn >= NN) gn = NN - 1;
        xsT[k][n] = x[gn * F_IN + k];
    }
    __syncthreads();

    int fq = tid & 31, nq = tid >> 5;
    int f0 = fq * 4, nb = nq * 8;
    float acc[8][4];
#pragma unroll
    for (int i = 0; i < 8; ++i)
#pragma unroll
        for (int j = 0; j < 4; ++j) acc[i][j] = 0.f;

    for (int k = 0; k < F_IN; ++k) {
        float4 w = *(const float4*)&WgS[k * HID + f0];
        float4 xa = *(const float4*)&xsT[k][nb];
        float4 xb = *(const float4*)&xsT[k][nb + 4];
        float xv[8] = {xa.x, xa.y, xa.z, xa.w, xb.x, xb.y, xb.z, xb.w};
        float wv[4] = {w.x, w.y, w.z, w.w};
#pragma unroll
        for (int i = 0; i < 8; ++i)
#pragma unroll
            for (int j = 0; j < 4; ++j)
                acc[i][j] = fmaf(xv[i], wv[j], acc[i][j]);
    }

    float4 as4 = *(const float4*)(a_s + f0);
    float4 ad4 = *(const float4*)(a_d + f0);
    float ps[8], pd[8];
#pragma unroll
    for (int i = 0; i < 8; ++i) {
        int gn = node0 + nb + i;
        if (gn < NN) {
            float4 v = {acc[i][0], acc[i][1], acc[i][2], acc[i][3]};
            *(float4*)(h + (size_t)gn * HID + f0) = v;
        }
        ps[i] = acc[i][0] * as4.x + acc[i][1] * as4.y + acc[i][2] * as4.z + acc[i][3] * as4.w;
        pd[i] = acc[i][0] * ad4.x + acc[i][1] * ad4.y + acc[i][2] * ad4.z + acc[i][3] * ad4.w;
    }
#pragma unroll
    for (int off = 16; off > 0; off >>= 1) {
#pragma unroll
        for (int i = 0; i < 8; ++i) {
            ps[i] += __shfl_xor(ps[i], off);
            pd[i] += __shfl_xor(pd[i], off);
        }
    }
    if (fq == 0) {
#pragma unroll
        for (int i = 0; i < 8; ++i) {
            int gn = node0 + nb + i;
            if (gn < NN) { hs[gn] = ps[i]; hd[gn] = pd[i]; }
        }
    }
}

// ---------------- CSR build ----------------
__global__ void k_hist(const int* __restrict__ dst, int* __restrict__ deg) {
    int e = blockIdx.x * blockDim.x + threadIdx.x;
    if (e < NE) atomicAdd(&deg[dst[e]], 1);
}

__global__ void k_scan1(const int* __restrict__ deg, int* __restrict__ rptr, int* __restrict__ bsum) {
    int t = threadIdx.x;
    int i = blockIdx.x * 256 + t;
    int v = (i < NN) ? deg[i] : 0;
    __shared__ int s[256];
    s[t] = v;
    __syncthreads();
    for (int off = 1; off < 256; off <<= 1) {
        int x = (t >= off) ? s[t - off] : 0;
        __syncthreads();
        s[t] += x;
        __syncthreads();
    }
    if (i < NN) rptr[i] = s[t] - v;
    if (t == 255) bsum[blockIdx.x] = s[255];
}

__global__ void k_scan2(int* __restrict__ bsum, int* __restrict__ bpre) {
    int t = threadIdx.x;
    int v = (t < NB_SCAN) ? bsum[t] : 0;
    __shared__ int s[256];
    s[t] = v;
    __syncthreads();
    for (int off = 1; off < 256; off <<= 1) {
        int x = (t >= off) ? s[t - off] : 0;
        __syncthreads();
        s[t] += x;
        __syncthreads();
    }
    if (t < NB_SCAN) bpre[t] = s[t] - v;
}

__global__ void k_scan3(int* __restrict__ rptr, const int* __restrict__ bpre) {
    int i = blockIdx.x * 256 + threadIdx.x;
    if (i < NN) rptr[i] += bpre[blockIdx.x];
}

__global__ void k_fill(const int* __restrict__ src, const int* __restrict__ dst,
                       const int* __restrict__ rptr, int* __restrict__ fill,
                       int* __restrict__ esrc) {
    int e = blockIdx.x * blockDim.x + threadIdx.x;
    if (e >= NE) return;
    int d = dst[e];
    int pos = rptr[d] + atomicAdd(&fill[d], 1);
    esrc[pos] = src[e];
}

// ---------------- GAT aggregation: edge-parallel weights (exp once per edge) ----------------
// block = 1 node, 128 threads (thread t = feature t; also edge-slot t in weight phase)
__global__ __launch_bounds__(128) void k_gat_agg(
    const int* __restrict__ rptr, const int* __restrict__ deg,
    const int* __restrict__ esrc, const float* __restrict__ hs,
    const float* __restrict__ hd, const float* __restrict__ h,
    const float* __restrict__ bg, float* __restrict__ h1) {
    int row = blockIdx.x;
    int t = threadIdx.x;
    int lane = t & 63, wid = t >> 6;
    int start = rptr[row];
    int dn = deg[row];
    int end = start + dn;
    float hdr = hd[row];
    float lself = leaky(hs[row] + hdr);

    __shared__ float ws[128];
    __shared__ int es[128];
    __shared__ float red[2];

    // phase 1: block-parallel max over edge logits
    float mloc = -3.4e38f;
    for (int e = start + t; e < end; e += 128)
        mloc = fmaxf(mloc, leaky(hs[esrc[e]] + hdr));
#pragma unroll
    for (int off = 32; off > 0; off >>= 1) mloc = fmaxf(mloc, __shfl_xor(mloc, off));
    if (lane == 0) red[wid] = mloc;
    __syncthreads();
    float m = fmaxf(fmaxf(red[0], red[1]), lself);

    // phase 2: chunked weights (exp once per edge) + feature accumulation
    float wself = __expf(lself - m);
    float denL = 0.f;
    float acc = wself * h[(size_t)row * HID + t];
    for (int c = start; c < end; c += 128) {
        int cl = min(128, end - c);
        __syncthreads();
        float w = 0.f;
        if (t < cl) {
            int s = esrc[c + t];
            es[t] = s;
            w = __expf(leaky(hs[s] + hdr) - m);
            ws[t] = w;
        }
        denL += w;
        __syncthreads();
        int j = 0;
        for (; j + 4 <= cl; j += 4) {
            float w0 = ws[j], w1 = ws[j + 1], w2 = ws[j + 2], w3 = ws[j + 3];
            int s0 = es[j], s1 = es[j + 1], s2 = es[j + 2], s3 = es[j + 3];
            acc = fmaf(w0, h[(size_t)s0 * HID + t], acc);
            acc = fmaf(w1, h[(size_t)s1 * HID + t], acc);
            acc = fmaf(w2, h[(size_t)s2 * HID + t], acc);
            acc = fmaf(w3, h[(size_t)s3 * HID + t], acc);
        }
        for (; j < cl; ++j) acc = fmaf(ws[j], h[(size_t)es[j] * HID + t], acc);
    }
    // reduce den
#pragma unroll
    for (int off = 32; off > 0; off >>= 1) denL += __shfl_xor(denL, off);
    __syncthreads();
    if (lane == 0) red[wid] = denL;
    __syncthreads();
    float den = wself + red[0] + red[1];

    float v = acc / den + bg[t];
    h1[(size_t)row * HID + t] = v > 0.f ? v : 0.f;
}

// ---------------- Fused SAGE: mean-gather into LDS + dual matvec + head ----------------
// 256 threads, TN=32 nodes/block; gather phase: 2 nodes in flight (tid>>7), feat = tid&127.
__global__ __launch_bounds__(256, 4) void k_sage_dense(
    const int* __restrict__ rptr, const int* __restrict__ deg,
    const int* __restrict__ esrc, const float* __restrict__ h1,
    const float* __restrict__ Wl, const float* __restrict__ bl,
    const float* __restrict__ Wr, const float* __restrict__ Wout,
    const float* __restrict__ bout, float* __restrict__ out) {
    __shared__ __align__(16) float aM[TN][AST];
    __shared__ __align__(16) float aS[TN][AST];
    int tid = threadIdx.x;
    int node0 = blockIdx.x * TN;
    {
        int sub = tid >> 7;      // 0..1
        int t = tid & 127;       // feature
        for (int np = 0; np < TN / 2; ++np) {
            int n = np * 2 + sub;
            int gn = node0 + n;
            int g = (gn < NN) ? gn : NN - 1;
            int st = rptr[g], dn = deg[g];
            int end = st + dn;
            float acc = 0.f;
            int e = st;
            for (; e + 4 <= end; e += 4) {
                int s0 = esrc[e], s1 = esrc[e + 1], s2 = esrc[e + 2], s3 = esrc[e + 3];
                float v0 = h1[(size_t)s0 * HID + t];
                float v1 = h1[(size_t)s1 * HID + t];
                float v2 = h1[(size_t)s2 * HID + t];
                float v3 = h1[(size_t)s3 * HID + t];
                acc += v0 + v1 + v2 + v3;
            }
            for (; e < end; ++e) acc += h1[(size_t)esrc[e] * HID + t];
            aM[n][t] = acc / (float)(dn > 0 ? dn : 1);
            aS[n][t] = h1[(size_t)g * HID + t];
        }
    }
    __syncthreads();

    int nq = tid >> 5;
    int fq = tid & 31;
    int f0 = fq * 4;
    int nb = nq * 4;
    float acc[4][4];
#pragma unroll
    for (int i = 0; i < 4; ++i)
#pragma unroll
        for (int j = 0; j < 4; ++j) acc[i][j] = 0.f;

#pragma unroll 2
    for (int kq = 0; kq < HID / 4; ++kq) {
        int k0 = kq * 4;
        float am[4][4], as_[4][4];
#pragma unroll
        for (int i = 0; i < 4; ++i) {
            float4 tm = *(const float4*)&aM[nb + i][k0];
            float4 ts = *(const float4*)&aS[nb + i][k0];
            am[i][0] = tm.x; am[i][1] = tm.y; am[i][2] = tm.z; am[i][3] = tm.w;
            as_[i][0] = ts.x; as_[i][1] = ts.y; as_[i][2] = ts.z; as_[i][3] = ts.w;
        }
#pragma unroll
        for (int j = 0; j < 4; ++j) {
            int k = k0 + j;
            float4 wl = *(const float4*)(Wl + k * HID + f0);
            float4 wr = *(const float4*)(Wr + k * HID + f0);
            float wlv[4] = {wl.x, wl.y, wl.z, wl.w};
            float wrv[4] = {wr.x, wr.y, wr.z, wr.w};
#pragma unroll
            for (int i = 0; i < 4; ++i)
#pragma unroll
                for (int jf = 0; jf < 4; ++jf)
                    acc[i][jf] = fmaf(am[i][j], wlv[jf], fmaf(as_[i][j], wrv[jf], acc[i][jf]));
        }
    }

    float4 bias = *(const float4*)(bl + f0);
    float4 wo = *(const float4*)(Wout + f0);
    float bo = bout[0];
#pragma unroll
    for (int i = 0; i < 4; ++i) {
        float h0 = fmaxf(acc[i][0] + bias.x, 0.f);
        float h1v = fmaxf(acc[i][1] + bias.y, 0.f);
        float h2v = fmaxf(acc[i][2] + bias.z, 0.f);
        float h3v = fmaxf(acc[i][3] + bias.w, 0.f);
        float p = h0 * wo.x + h1v * wo.y + h2v * wo.z + h3v * wo.w;
#pragma unroll
        for (int off = 16; off > 0; off >>= 1) p += __shfl_xor(p, off);
        if (fq == 0) {
            int gn = node0 + nb + i;
            if (gn < NN) {
                float z = p + bo;
                out[gn] = 1.f / (1.f + __expf(-z));
            }
        }
    }
}

extern "C" void kernel_launch(void* const* d_in, const int* in_sizes, int n_in,
                              void* d_out, int out_size, void* d_ws, size_t ws_size,
                              hipStream_t stream) {
    const float* x    = (const float*)d_in[0];
    const int*   ei   = (const int*)d_in[1];
    const float* Wg   = (const float*)d_in[2];
    const float* a_s  = (const float*)d_in[3];
    const float* a_d  = (const float*)d_in[4];
    const float* bg   = (const float*)d_in[5];
    const float* Wl   = (const float*)d_in[6];
    const float* bl   = (const float*)d_in[7];
    const float* Wr   = (const float*)d_in[8];
    const float* Wout = (const float*)d_in[9];
    const float* bout = (const float*)d_in[10];
    float* out = (float*)d_out;

    const int* src = ei;
    const int* dst = ei + NE;

    float* h  = (float*)d_ws;                 // NN*HID
    float* h1 = h + (size_t)NN * HID;         // NN*HID
    float* hs = h1 + (size_t)NN * HID;        // NN
    float* hd = hs + NN;                      // NN
    int* deg  = (int*)(hd + NN);              // NN  (zeroed)
    int* fill = deg + NN;                     // NN  (zeroed)
    int* rptr = fill + NN;                    // NN
    int* bsum = rptr + NN;                    // NB_SCAN
    int* bpre = bsum + NB_SCAN;               // NB_SCAN
    int* esrc = bpre + NB_SCAN;               // NE

    hipMemsetAsync(deg, 0, (size_t)2 * NN * sizeof(int), stream);

    k_gat_in<<<NB_GIN, 256, 0, stream>>>(x, Wg, a_s, a_d, h, hs, hd);

    k_hist<<<(NE + 255) / 256, 256, 0, stream>>>(dst, deg);
    k_scan1<<<NB_SCAN, 256, 0, stream>>>(deg, rptr, bsum);
    k_scan2<<<1, 256, 0, stream>>>(bsum, bpre);
    k_scan3<<<NB_SCAN, 256, 0, stream>>>(rptr, bpre);
    k_fill<<<(NE + 255) / 256, 256, 0, stream>>>(src, dst, rptr, fill, esrc);

    k_gat_agg<<<NN, 128, 0, stream>>>(rptr, deg, esrc, hs, hd, h, bg, h1);
    k_sage_dense<<<NB_DENSE, 256, 0, stream>>>(rptr, deg, esrc, h1, Wl, bl, Wr, Wout, bout, out);
}

// Round 6
// 243.053 us; speedup vs baseline: 1.2857x; 1.2857x over previous
//
#include <hip/hip_runtime.h>

#define NN 50000
#define NE 600000
#define F_IN 57
#define HID 128
#define NEG 0.2f
#define NB_SCAN ((NN + 255) / 256)

#define GIN_NODES 64
#define NB_GIN ((NN + GIN_NODES - 1) / GIN_NODES)
#define XST 68

#define TN 32                  // nodes per dense block
#define NB_DENSE ((NN + TN - 1) / TN)
#define AST 132                // activation row stride (floats)

typedef unsigned short bf16_t;

__device__ __forceinline__ float leaky(float v) { return v >= 0.f ? v : NEG * v; }
__device__ __forceinline__ float bf2f(bf16_t u) { return __uint_as_float(((unsigned)u) << 16); }
__device__ __forceinline__ bf16_t f2bf(float f) {
    unsigned u = __float_as_uint(f);
    return (bf16_t)((u + 0x7FFFu + ((u >> 16) & 1u)) >> 16);   // RNE
}

// ---------------- K1: tiled  h = x @ W_gat (bf16 out) ; hs = h.a_src ; hd = h.a_dst ----------------
__global__ __launch_bounds__(256) void k_gat_in(
    const float* __restrict__ x, const float* __restrict__ Wg,
    const float* __restrict__ a_s, const float* __restrict__ a_d,
    bf16_t* __restrict__ h, float* __restrict__ hs, float* __restrict__ hd) {
    __shared__ float WgS[F_IN * HID];
    __shared__ float xsT[F_IN][XST];
    int tid = threadIdx.x;
    int node0 = blockIdx.x * GIN_NODES;
    {
        const float4* g = (const float4*)Wg;
        float4* s = (float4*)WgS;
        for (int i = tid; i < F_IN * HID / 4; i += 256) s[i] = g[i];
    }
    for (int i = tid; i < GIN_NODES * F_IN; i += 256) {
        int n = i / F_IN;
        int k = i - n * F_IN;
        int gn = node0 + n;
        if (gn >= NN) gn = NN - 1;
        xsT[k][n] = x[gn * F_IN + k];
    }
    __syncthreads();

    int fq = tid & 31, nq = tid >> 5;
    int f0 = fq * 4, nb = nq * 8;
    float acc[8][4];
#pragma unroll
    for (int i = 0; i < 8; ++i)
#pragma unroll
        for (int j = 0; j < 4; ++j) acc[i][j] = 0.f;

    for (int k = 0; k < F_IN; ++k) {
        float4 w = *(const float4*)&WgS[k * HID + f0];
        float4 xa = *(const float4*)&xsT[k][nb];
        float4 xb = *(const float4*)&xsT[k][nb + 4];
        float xv[8] = {xa.x, xa.y, xa.z, xa.w, xb.x, xb.y, xb.z, xb.w};
        float wv[4] = {w.x, w.y, w.z, w.w};
#pragma unroll
        for (int i = 0; i < 8; ++i)
#pragma unroll
            for (int j = 0; j < 4; ++j)
                acc[i][j] = fmaf(xv[i], wv[j], acc[i][j]);
    }

    float4 as4 = *(const float4*)(a_s + f0);
    float4 ad4 = *(const float4*)(a_d + f0);
    float ps[8], pd[8];
#pragma unroll
    for (int i = 0; i < 8; ++i) {
        int gn = node0 + nb + i;
        if (gn < NN) {
            ushort4 hv;
            hv.x = f2bf(acc[i][0]); hv.y = f2bf(acc[i][1]);
            hv.z = f2bf(acc[i][2]); hv.w = f2bf(acc[i][3]);
            *(ushort4*)(h + (size_t)gn * HID + f0) = hv;
        }
        ps[i] = acc[i][0] * as4.x + acc[i][1] * as4.y + acc[i][2] * as4.z + acc[i][3] * as4.w;
        pd[i] = acc[i][0] * ad4.x + acc[i][1] * ad4.y + acc[i][2] * ad4.z + acc[i][3] * ad4.w;
    }
#pragma unroll
    for (int off = 16; off > 0; off >>= 1) {
#pragma unroll
        for (int i = 0; i < 8; ++i) {
            ps[i] += __shfl_xor(ps[i], off);
            pd[i] += __shfl_xor(pd[i], off);
        }
    }
    if (fq == 0) {
#pragma unroll
        for (int i = 0; i < 8; ++i) {
            int gn = node0 + nb + i;
            if (gn < NN) { hs[gn] = ps[i]; hd[gn] = pd[i]; }
        }
    }
}

// ---------------- CSR build ----------------
__global__ void k_hist(const int* __restrict__ dst, int* __restrict__ deg) {
    int e = blockIdx.x * blockDim.x + threadIdx.x;
    if (e < NE) atomicAdd(&deg[dst[e]], 1);
}

__global__ void k_scan1(const int* __restrict__ deg, int* __restrict__ rptr, int* __restrict__ bsum) {
    int t = threadIdx.x;
    int i = blockIdx.x * 256 + t;
    int v = (i < NN) ? deg[i] : 0;
    __shared__ int s[256];
    s[t] = v;
    __syncthreads();
    for (int off = 1; off < 256; off <<= 1) {
        int x = (t >= off) ? s[t - off] : 0;
        __syncthreads();
        s[t] += x;
        __syncthreads();
    }
    if (i < NN) rptr[i] = s[t] - v;
    if (t == 255) bsum[blockIdx.x] = s[255];
}

__global__ void k_scan2(int* __restrict__ bsum, int* __restrict__ bpre) {
    int t = threadIdx.x;
    int v = (t < NB_SCAN) ? bsum[t] : 0;
    __shared__ int s[256];
    s[t] = v;
    __syncthreads();
    for (int off = 1; off < 256; off <<= 1) {
        int x = (t >= off) ? s[t - off] : 0;
        __syncthreads();
        s[t] += x;
        __syncthreads();
    }
    if (t < NB_SCAN) bpre[t] = s[t] - v;
}

__global__ void k_scan3(int* __restrict__ rptr, const int* __restrict__ bpre) {
    int i = blockIdx.x * 256 + threadIdx.x;
    if (i < NN) rptr[i] += bpre[blockIdx.x];
}

__global__ void k_fill(const int* __restrict__ src, const int* __restrict__ dst,
                       const int* __restrict__ rptr, int* __restrict__ fill,
                       int* __restrict__ esrc) {
    int e = blockIdx.x * blockDim.x + threadIdx.x;
    if (e >= NE) return;
    int d = dst[e];
    int pos = rptr[d] + atomicAdd(&fill[d], 1);
    esrc[pos] = src[e];
}

// ---------------- GAT aggregation: single pass (no max-shift), exp once per edge ----------------
// block = 1 node, 128 threads (thread t = feature t; also edge-slot t in weight phase)
__global__ __launch_bounds__(128) void k_gat_agg(
    const int* __restrict__ rptr, const int* __restrict__ deg,
    const int* __restrict__ esrc, const float* __restrict__ hs,
    const float* __restrict__ hd, const bf16_t* __restrict__ h,
    const float* __restrict__ bg, bf16_t* __restrict__ h1) {
    int row = blockIdx.x;
    int t = threadIdx.x;
    int lane = t & 63, wid = t >> 6;
    int start = rptr[row];
    int dn = deg[row];
    int end = start + dn;
    float hdr = hd[row];
    // softmax without max-shift: logits bounded (|hs|,|hd| ~ O(4)), exp safe in f32;
    // shift-invariance makes this mathematically identical to the reference.
    float wself = __expf(leaky(hs[row] + hdr));

    __shared__ float ws[128];
    __shared__ int es[128];
    __shared__ float red[2];

    float denL = 0.f;
    float acc = wself * bf2f(h[(size_t)row * HID + t]);
    for (int c = start; c < end; c += 128) {
        int cl = min(128, end - c);
        __syncthreads();
        float w = 0.f;
        if (t < cl) {
            int s = esrc[c + t];
            es[t] = s;
            w = __expf(leaky(hs[s] + hdr));
            ws[t] = w;
        }
        denL += w;
        __syncthreads();
        int j = 0;
        for (; j + 4 <= cl; j += 4) {
            float w0 = ws[j], w1 = ws[j + 1], w2 = ws[j + 2], w3 = ws[j + 3];
            int s0 = es[j], s1 = es[j + 1], s2 = es[j + 2], s3 = es[j + 3];
            acc = fmaf(w0, bf2f(h[(size_t)s0 * HID + t]), acc);
            acc = fmaf(w1, bf2f(h[(size_t)s1 * HID + t]), acc);
            acc = fmaf(w2, bf2f(h[(size_t)s2 * HID + t]), acc);
            acc = fmaf(w3, bf2f(h[(size_t)s3 * HID + t]), acc);
        }
        for (; j < cl; ++j) acc = fmaf(ws[j], bf2f(h[(size_t)es[j] * HID + t]), acc);
    }
#pragma unroll
    for (int off = 32; off > 0; off >>= 1) denL += __shfl_xor(denL, off);
    __syncthreads();
    if (lane == 0) red[wid] = denL;
    __syncthreads();
    float den = wself + red[0] + red[1];

    float v = acc / den + bg[t];
    h1[(size_t)row * HID + t] = f2bf(v > 0.f ? v : 0.f);
}

// ---------------- SAGE mean gather (bf16 in/out, 4-way unrolled) ----------------
__global__ __launch_bounds__(128) void k_sage_gather(
    const int* __restrict__ rptr, const int* __restrict__ deg,
    const int* __restrict__ esrc, const bf16_t* __restrict__ h1,
    bf16_t* __restrict__ mean) {
    int row = blockIdx.x;
    int t = threadIdx.x;
    int start = rptr[row];
    int dn = deg[row];
    int end = start + dn;
    float acc = 0.f;
    int e = start;
    for (; e + 4 <= end; e += 4) {
        int s0 = esrc[e], s1 = esrc[e + 1], s2 = esrc[e + 2], s3 = esrc[e + 3];
        float v0 = bf2f(h1[(size_t)s0 * HID + t]);
        float v1 = bf2f(h1[(size_t)s1 * HID + t]);
        float v2 = bf2f(h1[(size_t)s2 * HID + t]);
        float v3 = bf2f(h1[(size_t)s3 * HID + t]);
        acc += v0 + v1 + v2 + v3;
    }
    for (; e < end; ++e) acc += bf2f(h1[(size_t)esrc[e] * HID + t]);
    mean[(size_t)row * HID + t] = f2bf(acc / (float)(dn > 0 ? dn : 1));
}

// ---------------- Dense: out = sigmoid(relu(mean@Wl + bl + h1@Wr) @ Wout + bout) ----------------
// 256 threads, TN=32 nodes/block; bf16 activation loads unpacked to f32 LDS tiles.
__device__ __forceinline__ void unpack8(uint4 v, float* dstp) {
    unsigned a0 = v.x, a1 = v.y, a2 = v.z, a3 = v.w;
    dstp[0] = __uint_as_float((a0 & 0xFFFFu) << 16); dstp[1] = __uint_as_float(a0 & 0xFFFF0000u);
    dstp[2] = __uint_as_float((a1 & 0xFFFFu) << 16); dstp[3] = __uint_as_float(a1 & 0xFFFF0000u);
    dstp[4] = __uint_as_float((a2 & 0xFFFFu) << 16); dstp[5] = __uint_as_float(a2 & 0xFFFF0000u);
    dstp[6] = __uint_as_float((a3 & 0xFFFFu) << 16); dstp[7] = __uint_as_float(a3 & 0xFFFF0000u);
}

__global__ __launch_bounds__(256, 4) void k_dense(
    const bf16_t* __restrict__ mean, const bf16_t* __restrict__ h1,
    const float* __restrict__ Wl, const float* __restrict__ bl,
    const float* __restrict__ Wr, const float* __restrict__ Wout,
    const float* __restrict__ bout, float* __restrict__ out) {
    __shared__ __align__(16) float aM[TN][AST];
    __shared__ __align__(16) float aS[TN][AST];
    int tid = threadIdx.x;
    int node0 = blockIdx.x * TN;
    {
        int n = tid >> 3;
        int kq = tid & 7;          // 8 threads/node, 16 feats each
        int gn = node0 + n;
        if (gn >= NN) gn = NN - 1;
        const uint4* mrow = (const uint4*)(mean + (size_t)gn * HID);
        const uint4* srow = (const uint4*)(h1 + (size_t)gn * HID);
#pragma unroll
        for (int half = 0; half < 2; ++half) {
            int q = kq * 2 + half;       // uint4 index 0..15, covers feats q*8..q*8+7
            unpack8(mrow[q], &aM[n][q * 8]);
            unpack8(srow[q], &aS[n][q * 8]);
        }
    }
    __syncthreads();

    int nq = tid >> 5;
    int fq = tid & 31;
    int f0 = fq * 4;
    int nb = nq * 4;
    float acc[4][4];
#pragma unroll
    for (int i = 0; i < 4; ++i)
#pragma unroll
        for (int j = 0; j < 4; ++j) acc[i][j] = 0.f;

#pragma unroll 2
    for (int kq = 0; kq < HID / 4; ++kq) {
        int k0 = kq * 4;
        float am[4][4], as_[4][4];
#pragma unroll
        for (int i = 0; i < 4; ++i) {
            float4 tm = *(const float4*)&aM[nb + i][k0];
            float4 ts = *(const float4*)&aS[nb + i][k0];
            am[i][0] = tm.x; am[i][1] = tm.y; am[i][2] = tm.z; am[i][3] = tm.w;
            as_[i][0] = ts.x; as_[i][1] = ts.y; as_[i][2] = ts.z; as_[i][3] = ts.w;
        }
#pragma unroll
        for (int j = 0; j < 4; ++j) {
            int k = k0 + j;
            float4 wl = *(const float4*)(Wl + k * HID + f0);
            float4 wr = *(const float4*)(Wr + k * HID + f0);
            float wlv[4] = {wl.x, wl.y, wl.z, wl.w};
            float wrv[4] = {wr.x, wr.y, wr.z, wr.w};
#pragma unroll
            for (int i = 0; i < 4; ++i)
#pragma unroll
                for (int jf = 0; jf < 4; ++jf)
                    acc[i][jf] = fmaf(am[i][j], wlv[jf], fmaf(as_[i][j], wrv[jf], acc[i][jf]));
        }
    }

    float4 bias = *(const float4*)(bl + f0);
    float4 wo = *(const float4*)(Wout + f0);
    float bo = bout[0];
#pragma unroll
    for (int i = 0; i < 4; ++i) {
        float h0 = fmaxf(acc[i][0] + bias.x, 0.f);
        float h1v = fmaxf(acc[i][1] + bias.y, 0.f);
        float h2v = fmaxf(acc[i][2] + bias.z, 0.f);
        float h3v = fmaxf(acc[i][3] + bias.w, 0.f);
        float p = h0 * wo.x + h1v * wo.y + h2v * wo.z + h3v * wo.w;
#pragma unroll
        for (int off = 16; off > 0; off >>= 1) p += __shfl_xor(p, off);
        if (fq == 0) {
            int gn = node0 + nb + i;
            if (gn < NN) {
                float z = p + bo;
                out[gn] = 1.f / (1.f + __expf(-z));
            }
        }
    }
}

extern "C" void kernel_launch(void* const* d_in, const int* in_sizes, int n_in,
                              void* d_out, int out_size, void* d_ws, size_t ws_size,
                              hipStream_t stream) {
    const float* x    = (const float*)d_in[0];
    const int*   ei   = (const int*)d_in[1];
    const float* Wg   = (const float*)d_in[2];
    const float* a_s  = (const float*)d_in[3];
    const float* a_d  = (const float*)d_in[4];
    const float* bg   = (const float*)d_in[5];
    const float* Wl   = (const float*)d_in[6];
    const float* bl   = (const float*)d_in[7];
    const float* Wr   = (const float*)d_in[8];
    const float* Wout = (const float*)d_in[9];
    const float* bout = (const float*)d_in[10];
    float* out = (float*)d_out;

    const int* src = ei;
    const int* dst = ei + NE;

    bf16_t* h    = (bf16_t*)d_ws;                  // NN*HID bf16
    bf16_t* h1   = h + (size_t)NN * HID;           // NN*HID bf16
    bf16_t* mean = h1 + (size_t)NN * HID;          // NN*HID bf16
    float* hs = (float*)(mean + (size_t)NN * HID); // NN
    float* hd = hs + NN;                           // NN
    int* deg  = (int*)(hd + NN);                   // NN  (zeroed)
    int* fill = deg + NN;                          // NN  (zeroed)
    int* rptr = fill + NN;                         // NN
    int* bsum = rptr + NN;                         // NB_SCAN
    int* bpre = bsum + NB_SCAN;                    // NB_SCAN
    int* esrc = bpre + NB_SCAN;                    // NE

    hipMemsetAsync(deg, 0, (size_t)2 * NN * sizeof(int), stream);

    k_gat_in<<<NB_GIN, 256, 0, stream>>>(x, Wg, a_s, a_d, h, hs, hd);

    k_hist<<<(NE + 255) / 256, 256, 0, stream>>>(dst, deg);
    k_scan1<<<NB_SCAN, 256, 0, stream>>>(deg, rptr, bsum);
    k_scan2<<<1, 256, 0, stream>>>(bsum, bpre);
    k_scan3<<<NB_SCAN, 256, 0, stream>>>(rptr, bpre);
    k_fill<<<(NE + 255) / 256, 256, 0, stream>>>(src, dst, rptr, fill, esrc);

    k_gat_agg<<<NN, 128, 0, stream>>>(rptr, deg, esrc, hs, hd, h, bg, h1);
    k_sage_gather<<<NN, 128, 0, stream>>>(rptr, deg, esrc, h1, mean);
    k_dense<<<NB_DENSE, 256, 0, stream>>>(mean, h1, Wl, bl, Wr, Wout, bout, out);
}

// Round 7
// 200.164 us; speedup vs baseline: 1.5612x; 1.2143x over previous
//
#include <hip/hip_runtime.h>

#define NN 50000
#define NE 600000
#define F_IN 57
#define HID 128
#define NEG 0.2f
#define NB_SCAN ((NN + 255) / 256)

#define GIN_NODES 64
#define NB_GIN ((NN + GIN_NODES - 1) / NN == 0 ? ((NN + GIN_NODES - 1) / GIN_NODES) : ((NN + GIN_NODES - 1) / GIN_NODES))
#undef NB_GIN
#define NB_GIN ((NN + GIN_NODES - 1) / GIN_NODES)
#define XST 68

#define DN_NODES 64            // nodes per MFMA dense block (4 waves x 16)
#define NB_DENSE ((NN + DN_NODES - 1) / DN_NODES)

typedef unsigned short bf16_t;
typedef __attribute__((ext_vector_type(8))) short bf16x8;
typedef __attribute__((ext_vector_type(4))) float f32x4;

__device__ __forceinline__ float leaky(float v) { return v >= 0.f ? v : NEG * v; }
__device__ __forceinline__ float bf2f(bf16_t u) { return __uint_as_float(((unsigned)u) << 16); }
__device__ __forceinline__ bf16_t f2bf(float f) {
    unsigned u = __float_as_uint(f);
    return (bf16_t)((u + 0x7FFFu + ((u >> 16) & 1u)) >> 16);   // RNE
}

// ---------------- K1: tiled  h = x @ W_gat (bf16 out) ; hs = h.a_src ; hd = h.a_dst ----------------
__global__ __launch_bounds__(256) void k_gat_in(
    const float* __restrict__ x, const float* __restrict__ Wg,
    const float* __restrict__ a_s, const float* __restrict__ a_d,
    bf16_t* __restrict__ h, float* __restrict__ hs, float* __restrict__ hd) {
    __shared__ float WgS[F_IN * HID];
    __shared__ float xsT[F_IN][XST];
    int tid = threadIdx.x;
    int node0 = blockIdx.x * GIN_NODES;
    {
        const float4* g = (const float4*)Wg;
        float4* s = (float4*)WgS;
        for (int i = tid; i < F_IN * HID / 4; i += 256) s[i] = g[i];
    }
    for (int i = tid; i < GIN_NODES * F_IN; i += 256) {
        int n = i / F_IN;
        int k = i - n * F_IN;
        int gn = node0 + n;
        if (gn >= NN) gn = NN - 1;
        xsT[k][n] = x[gn * F_IN + k];
    }
    __syncthreads();

    int fq = tid & 31, nq = tid >> 5;
    int f0 = fq * 4, nb = nq * 8;
    float acc[8][4];
#pragma unroll
    for (int i = 0; i < 8; ++i)
#pragma unroll
        for (int j = 0; j < 4; ++j) acc[i][j] = 0.f;

    for (int k = 0; k < F_IN; ++k) {
        float4 w = *(const float4*)&WgS[k * HID + f0];
        float4 xa = *(const float4*)&xsT[k][nb];
        float4 xb = *(const float4*)&xsT[k][nb + 4];
        float xv[8] = {xa.x, xa.y, xa.z, xa.w, xb.x, xb.y, xb.z, xb.w};
        float wv[4] = {w.x, w.y, w.z, w.w};
#pragma unroll
        for (int i = 0; i < 8; ++i)
#pragma unroll
            for (int j = 0; j < 4; ++j)
                acc[i][j] = fmaf(xv[i], wv[j], acc[i][j]);
    }

    float4 as4 = *(const float4*)(a_s + f0);
    float4 ad4 = *(const float4*)(a_d + f0);
    float ps[8], pd[8];
#pragma unroll
    for (int i = 0; i < 8; ++i) {
        int gn = node0 + nb + i;
        if (gn < NN) {
            ushort4 hv;
            hv.x = f2bf(acc[i][0]); hv.y = f2bf(acc[i][1]);
            hv.z = f2bf(acc[i][2]); hv.w = f2bf(acc[i][3]);
            *(ushort4*)(h + (size_t)gn * HID + f0) = hv;
        }
        ps[i] = acc[i][0] * as4.x + acc[i][1] * as4.y + acc[i][2] * as4.z + acc[i][3] * as4.w;
        pd[i] = acc[i][0] * ad4.x + acc[i][1] * ad4.y + acc[i][2] * ad4.z + acc[i][3] * ad4.w;
    }
#pragma unroll
    for (int off = 16; off > 0; off >>= 1) {
#pragma unroll
        for (int i = 0; i < 8; ++i) {
            ps[i] += __shfl_xor(ps[i], off);
            pd[i] += __shfl_xor(pd[i], off);
        }
    }
    if (fq == 0) {
#pragma unroll
        for (int i = 0; i < 8; ++i) {
            int gn = node0 + nb + i;
            if (gn < NN) { hs[gn] = ps[i]; hd[gn] = pd[i]; }
        }
    }
}

// ---------------- weight pack: [Wl;Wr] f32 -> bf16 MFMA B-fragment order ----------------
// Bp[((nt*8 + kb)*64 + lane)*8 + j] = B[kb*32 + (lane>>4)*8 + j][nt*16 + (lane&15)]
__global__ __launch_bounds__(256) void k_pack_w(
    const float* __restrict__ Wl, const float* __restrict__ Wr, bf16_t* __restrict__ Bp) {
    int idx = blockIdx.x * 256 + threadIdx.x;
    if (idx >= 8 * 8 * 64) return;
    int lane = idx & 63;
    int kb = (idx >> 6) & 7;
    int nt = idx >> 9;
    int col = nt * 16 + (lane & 15);
    int kbase = kb * 32 + (lane >> 4) * 8;
    bf16_t v[8];
#pragma unroll
    for (int j = 0; j < 8; ++j) {
        int k = kbase + j;
        float w = (k < HID) ? Wl[k * HID + col] : Wr[(k - HID) * HID + col];
        v[j] = f2bf(w);
    }
    ushort4* o = (ushort4*)(Bp + (size_t)idx * 8);
    ushort4 lo, hi;
    lo.x = v[0]; lo.y = v[1]; lo.z = v[2]; lo.w = v[3];
    hi.x = v[4]; hi.y = v[5]; hi.z = v[6]; hi.w = v[7];
    o[0] = lo; o[1] = hi;
}

// ---------------- CSR build ----------------
__global__ void k_hist(const int* __restrict__ dst, int* __restrict__ deg) {
    int e = blockIdx.x * blockDim.x + threadIdx.x;
    if (e < NE) atomicAdd(&deg[dst[e]], 1);
}

__global__ void k_scan1(const int* __restrict__ deg, int* __restrict__ rptr, int* __restrict__ bsum) {
    int t = threadIdx.x;
    int i = blockIdx.x * 256 + t;
    int v = (i < NN) ? deg[i] : 0;
    __shared__ int s[256];
    s[t] = v;
    __syncthreads();
    for (int off = 1; off < 256; off <<= 1) {
        int x = (t >= off) ? s[t - off] : 0;
        __syncthreads();
        s[t] += x;
        __syncthreads();
    }
    if (i < NN) rptr[i] = s[t] - v;
    if (t == 255) bsum[blockIdx.x] = s[255];
}

// scan3 with fused block-prefix: prefix = sum(bsum[j], j < blockIdx.x)
__global__ void k_scan3(int* __restrict__ rptr, const int* __restrict__ bsum) {
    int t = threadIdx.x;
    int v = (t < NB_SCAN && t < blockIdx.x) ? bsum[t] : 0;
#pragma unroll
    for (int off = 32; off > 0; off >>= 1) v += __shfl_xor(v, off);
    __shared__ int wsum[4];
    if ((t & 63) == 0) wsum[t >> 6] = v;
    __syncthreads();
    int pre = wsum[0] + wsum[1] + wsum[2] + wsum[3];
    int i = blockIdx.x * 256 + t;
    if (i < NN) rptr[i] += pre;
}

__global__ void k_fill(const int* __restrict__ src, const int* __restrict__ dst,
                       const int* __restrict__ rptr, int* __restrict__ fill,
                       int* __restrict__ esrc) {
    int e = blockIdx.x * blockDim.x + threadIdx.x;
    if (e >= NE) return;
    int d = dst[e];
    int pos = rptr[d] + atomicAdd(&fill[d], 1);
    esrc[pos] = src[e];
}

// ---------------- GAT aggregation: single pass (no max-shift), exp once per edge ----------------
__global__ __launch_bounds__(128) void k_gat_agg(
    const int* __restrict__ rptr, const int* __restrict__ deg,
    const int* __restrict__ esrc, const float* __restrict__ hs,
    const float* __restrict__ hd, const bf16_t* __restrict__ h,
    const float* __restrict__ bg, bf16_t* __restrict__ h1) {
    int row = blockIdx.x;
    int t = threadIdx.x;
    int lane = t & 63, wid = t >> 6;
    int start = rptr[row];
    int dn = deg[row];
    int end = start + dn;
    float hdr = hd[row];
    float wself = __expf(leaky(hs[row] + hdr));

    __shared__ float ws[128];
    __shared__ int es[128];
    __shared__ float red[2];

    float denL = 0.f;
    float acc = wself * bf2f(h[(size_t)row * HID + t]);
    for (int c = start; c < end; c += 128) {
        int cl = min(128, end - c);
        __syncthreads();
        float w = 0.f;
        if (t < cl) {
            int s = esrc[c + t];
            es[t] = s;
            w = __expf(leaky(hs[s] + hdr));
            ws[t] = w;
        }
        denL += w;
        __syncthreads();
        int j = 0;
        for (; j + 4 <= cl; j += 4) {
            float w0 = ws[j], w1 = ws[j + 1], w2 = ws[j + 2], w3 = ws[j + 3];
            int s0 = es[j], s1 = es[j + 1], s2 = es[j + 2], s3 = es[j + 3];
            acc = fmaf(w0, bf2f(h[(size_t)s0 * HID + t]), acc);
            acc = fmaf(w1, bf2f(h[(size_t)s1 * HID + t]), acc);
            acc = fmaf(w2, bf2f(h[(size_t)s2 * HID + t]), acc);
            acc = fmaf(w3, bf2f(h[(size_t)s3 * HID + t]), acc);
        }
        for (; j < cl; ++j) acc = fmaf(ws[j], bf2f(h[(size_t)es[j] * HID + t]), acc);
    }
#pragma unroll
    for (int off = 32; off > 0; off >>= 1) denL += __shfl_xor(denL, off);
    __syncthreads();
    if (lane == 0) red[wid] = denL;
    __syncthreads();
    float den = wself + red[0] + red[1];

    float v = acc / den + bg[t];
    h1[(size_t)row * HID + t] = f2bf(v > 0.f ? v : 0.f);
}

// ---------------- SAGE mean gather (bf16 in/out, 4-way unrolled) ----------------
__global__ __launch_bounds__(128) void k_sage_gather(
    const int* __restrict__ rptr, const int* __restrict__ deg,
    const int* __restrict__ esrc, const bf16_t* __restrict__ h1,
    bf16_t* __restrict__ mean) {
    int row = blockIdx.x;
    int t = threadIdx.x;
    int start = rptr[row];
    int dn = deg[row];
    int end = start + dn;
    float acc = 0.f;
    int e = start;
    for (; e + 4 <= end; e += 4) {
        int s0 = esrc[e], s1 = esrc[e + 1], s2 = esrc[e + 2], s3 = esrc[e + 3];
        float v0 = bf2f(h1[(size_t)s0 * HID + t]);
        float v1 = bf2f(h1[(size_t)s1 * HID + t]);
        float v2 = bf2f(h1[(size_t)s2 * HID + t]);
        float v3 = bf2f(h1[(size_t)s3 * HID + t]);
        acc += v0 + v1 + v2 + v3;
    }
    for (; e < end; ++e) acc += bf2f(h1[(size_t)esrc[e] * HID + t]);
    mean[(size_t)row * HID + t] = f2bf(acc / (float)(dn > 0 ? dn : 1));
}

// ---------------- Dense via MFMA: out = sigmoid(relu([mean|h1] @ [Wl;Wr] + bl) @ Wout + bout) ----
// 64 nodes/block, 4 waves. Wave w: nodes node0+w*16..+15 (M=16) x all 128 feats (8 N-tiles), K=256.
// A-frag: lane reads A[row=lane&15][k=(lane>>4)*8+j] (16B from mean/h1 row).
// B-frag: packed by k_pack_w; 16B/lane coalesced. C/D: col=lane&15, row=(lane>>4)*4+reg.
__global__ __launch_bounds__(256) void k_dense_mfma(
    const bf16_t* __restrict__ mean, const bf16_t* __restrict__ h1,
    const bf16_t* __restrict__ Bp, const float* __restrict__ bl,
    const float* __restrict__ Wout, const float* __restrict__ bout,
    float* __restrict__ out) {
    int tid = threadIdx.x;
    int lane = tid & 63;
    int wv = tid >> 6;
    int node0 = blockIdx.x * DN_NODES + wv * 16;
    int arow = lane & 15;
    int kg = lane >> 4;
    int gn = node0 + arow;
    if (gn >= NN) gn = NN - 1;
    const bf16_t* mrow = mean + (size_t)gn * HID;
    const bf16_t* srow = h1 + (size_t)gn * HID;
    const bf16x8* bp = (const bf16x8*)Bp;

    f32x4 acc[8];
#pragma unroll
    for (int n = 0; n < 8; ++n) acc[n] = (f32x4){0.f, 0.f, 0.f, 0.f};

#pragma unroll
    for (int kb = 0; kb < 8; ++kb) {
        int k0 = kb * 32 + kg * 8;
        bf16x8 a = (kb < 4) ? *(const bf16x8*)(mrow + k0)
                            : *(const bf16x8*)(srow + (k0 - HID));
#pragma unroll
        for (int n = 0; n < 8; ++n) {
            bf16x8 b = bp[((n * 8 + kb) << 6) + lane];
            acc[n] = __builtin_amdgcn_mfma_f32_16x16x32_bf16(a, b, acc[n], 0, 0, 0);
        }
    }

    // epilogue: bias + relu + dot(Wout) + sigmoid; lane holds C[kg*4+reg][n*16+arow]
    float pr[4] = {0.f, 0.f, 0.f, 0.f};
#pragma unroll
    for (int n = 0; n < 8; ++n) {
        int f = n * 16 + arow;
        float b = bl[f];
        float wo = Wout[f];
#pragma unroll
        for (int r = 0; r < 4; ++r) {
            float v = fmaxf(acc[n][r] + b, 0.f);
            pr[r] = fmaf(v, wo, pr[r]);
        }
    }
#pragma unroll
    for (int off = 8; off > 0; off >>= 1) {
#pragma unroll
        for (int r = 0; r < 4; ++r) pr[r] += __shfl_xor(pr[r], off);
    }
    if (arow == 0) {
        float bo = bout[0];
#pragma unroll
        for (int r = 0; r < 4; ++r) {
            int gno = node0 + kg * 4 + r;
            if (gno < NN) out[gno] = 1.f / (1.f + __expf(-(pr[r] + bo)));
        }
    }
}

extern "C" void kernel_launch(void* const* d_in, const int* in_sizes, int n_in,
                              void* d_out, int out_size, void* d_ws, size_t ws_size,
                              hipStream_t stream) {
    const float* x    = (const float*)d_in[0];
    const int*   ei   = (const int*)d_in[1];
    const float* Wg   = (const float*)d_in[2];
    const float* a_s  = (const float*)d_in[3];
    const float* a_d  = (const float*)d_in[4];
    const float* bg   = (const float*)d_in[5];
    const float* Wl   = (const float*)d_in[6];
    const float* bl   = (const float*)d_in[7];
    const float* Wr   = (const float*)d_in[8];
    const float* Wout = (const float*)d_in[9];
    const float* bout = (const float*)d_in[10];
    float* out = (float*)d_out;

    const int* src = ei;
    const int* dst = ei + NE;

    bf16_t* h    = (bf16_t*)d_ws;                  // NN*HID bf16
    bf16_t* h1   = h + (size_t)NN * HID;           // NN*HID bf16
    bf16_t* mean = h1 + (size_t)NN * HID;          // NN*HID bf16
    bf16_t* Bp   = mean + (size_t)NN * HID;        // 8*8*64*8 = 32768 bf16 (64 KB)
    float* hs = (float*)(Bp + 8 * 8 * 64 * 8);     // NN
    float* hd = hs + NN;                           // NN
    int* deg  = (int*)(hd + NN);                   // NN  (zeroed)
    int* fill = deg + NN;                          // NN  (zeroed)
    int* rptr = fill + NN;                         // NN
    int* bsum = rptr + NN;                         // NB_SCAN
    int* esrc = bsum + NB_SCAN;                    // NE

    hipMemsetAsync(deg, 0, (size_t)2 * NN * sizeof(int), stream);

    k_pack_w<<<16, 256, 0, stream>>>(Wl, Wr, Bp);
    k_gat_in<<<NB_GIN, 256, 0, stream>>>(x, Wg, a_s, a_d, h, hs, hd);

    k_hist<<<(NE + 255) / 256, 256, 0, stream>>>(dst, deg);
    k_scan1<<<NB_SCAN, 256, 0, stream>>>(deg, rptr, bsum);
    k_scan3<<<NB_SCAN, 256, 0, stream>>>(rptr, bsum);
    k_fill<<<(NE + 255) / 256, 256, 0, stream>>>(src, dst, rptr, fill, esrc);

    k_gat_agg<<<NN, 128, 0, stream>>>(rptr, deg, esrc, hs, hd, h, bg, h1);
    k_sage_gather<<<NN, 128, 0, stream>>>(rptr, deg, esrc, h1, mean);
    k_dense_mfma<<<NB_DENSE, 256, 0, stream>>>(mean, h1, Bp, bl, Wout, bout, out);
}

// Round 8
// 197.794 us; speedup vs baseline: 1.5799x; 1.0120x over previous
//
#include <hip/hip_runtime.h>

#define NN 50000
#define NE 600000
#define F_IN 57
#define HID 128
#define NEG 0.2f
#define NB_SCAN ((NN + 255) / 256)

#define GIN_NODES 64
#define NB_GIN ((NN + GIN_NODES - 1) / GIN_NODES)
#define XST 68

#define DN_NODES 64            // nodes per MFMA dense block (4 waves x 16)
#define NB_DENSE ((NN + DN_NODES - 1) / DN_NODES)

typedef unsigned short bf16_t;
typedef __attribute__((ext_vector_type(8))) short bf16x8;
typedef __attribute__((ext_vector_type(4))) float f32x4;

__device__ __forceinline__ float leaky(float v) { return v >= 0.f ? v : NEG * v; }
__device__ __forceinline__ float bf2f(bf16_t u) { return __uint_as_float(((unsigned)u) << 16); }
__device__ __forceinline__ bf16_t f2bf(float f) {
    unsigned u = __float_as_uint(f);
    return (bf16_t)((u + 0x7FFFu + ((u >> 16) & 1u)) >> 16);   // RNE
}

// ---------------- K1: tiled  h = x @ W_gat (bf16 out) ; hs = h.a_src ; hd = h.a_dst ----------------
__global__ __launch_bounds__(256) void k_gat_in(
    const float* __restrict__ x, const float* __restrict__ Wg,
    const float* __restrict__ a_s, const float* __restrict__ a_d,
    bf16_t* __restrict__ h, float* __restrict__ hs, float* __restrict__ hd) {
    __shared__ float WgS[F_IN * HID];
    __shared__ float xsT[F_IN][XST];
    int tid = threadIdx.x;
    int node0 = blockIdx.x * GIN_NODES;
    {
        const float4* g = (const float4*)Wg;
        float4* s = (float4*)WgS;
        for (int i = tid; i < F_IN * HID / 4; i += 256) s[i] = g[i];
    }
    for (int i = tid; i < GIN_NODES * F_IN; i += 256) {
        int n = i / F_IN;
        int k = i - n * F_IN;
        int gn = node0 + n;
        if (gn >= NN) gn = NN - 1;
        xsT[k][n] = x[gn * F_IN + k];
    }
    __syncthreads();

    int fq = tid & 31, nq = tid >> 5;
    int f0 = fq * 4, nb = nq * 8;
    float acc[8][4];
#pragma unroll
    for (int i = 0; i < 8; ++i)
#pragma unroll
        for (int j = 0; j < 4; ++j) acc[i][j] = 0.f;

    for (int k = 0; k < F_IN; ++k) {
        float4 w = *(const float4*)&WgS[k * HID + f0];
        float4 xa = *(const float4*)&xsT[k][nb];
        float4 xb = *(const float4*)&xsT[k][nb + 4];
        float xv[8] = {xa.x, xa.y, xa.z, xa.w, xb.x, xb.y, xb.z, xb.w};
        float wv[4] = {w.x, w.y, w.z, w.w};
#pragma unroll
        for (int i = 0; i < 8; ++i)
#pragma unroll
            for (int j = 0; j < 4; ++j)
                acc[i][j] = fmaf(xv[i], wv[j], acc[i][j]);
    }

    float4 as4 = *(const float4*)(a_s + f0);
    float4 ad4 = *(const float4*)(a_d + f0);
    float ps[8], pd[8];
#pragma unroll
    for (int i = 0; i < 8; ++i) {
        int gn = node0 + nb + i;
        if (gn < NN) {
            ushort4 hv;
            hv.x = f2bf(acc[i][0]); hv.y = f2bf(acc[i][1]);
            hv.z = f2bf(acc[i][2]); hv.w = f2bf(acc[i][3]);
            *(ushort4*)(h + (size_t)gn * HID + f0) = hv;
        }
        ps[i] = acc[i][0] * as4.x + acc[i][1] * as4.y + acc[i][2] * as4.z + acc[i][3] * as4.w;
        pd[i] = acc[i][0] * ad4.x + acc[i][1] * ad4.y + acc[i][2] * ad4.z + acc[i][3] * ad4.w;
    }
#pragma unroll
    for (int off = 16; off > 0; off >>= 1) {
#pragma unroll
        for (int i = 0; i < 8; ++i) {
            ps[i] += __shfl_xor(ps[i], off);
            pd[i] += __shfl_xor(pd[i], off);
        }
    }
    if (fq == 0) {
#pragma unroll
        for (int i = 0; i < 8; ++i) {
            int gn = node0 + nb + i;
            if (gn < NN) { hs[gn] = ps[i]; hd[gn] = pd[i]; }
        }
    }
}

// ---------------- weight pack: [Wl;Wr] f32 -> bf16 MFMA B-fragment order ----------------
__global__ __launch_bounds__(256) void k_pack_w(
    const float* __restrict__ Wl, const float* __restrict__ Wr, bf16_t* __restrict__ Bp) {
    int idx = blockIdx.x * 256 + threadIdx.x;
    if (idx >= 8 * 8 * 64) return;
    int lane = idx & 63;
    int kb = (idx >> 6) & 7;
    int nt = idx >> 9;
    int col = nt * 16 + (lane & 15);
    int kbase = kb * 32 + (lane >> 4) * 8;
    bf16_t v[8];
#pragma unroll
    for (int j = 0; j < 8; ++j) {
        int k = kbase + j;
        float w = (k < HID) ? Wl[k * HID + col] : Wr[(k - HID) * HID + col];
        v[j] = f2bf(w);
    }
    ushort4* o = (ushort4*)(Bp + (size_t)idx * 8);
    ushort4 lo, hi;
    lo.x = v[0]; lo.y = v[1]; lo.z = v[2]; lo.w = v[3];
    hi.x = v[4]; hi.y = v[5]; hi.z = v[6]; hi.w = v[7];
    o[0] = lo; o[1] = hi;
}

// ---------------- CSR build ----------------
__global__ void k_hist(const int* __restrict__ dst, int* __restrict__ deg) {
    int e = blockIdx.x * blockDim.x + threadIdx.x;
    if (e < NE) atomicAdd(&deg[dst[e]], 1);
}

__global__ void k_scan1(const int* __restrict__ deg, int* __restrict__ rptr, int* __restrict__ bsum) {
    int t = threadIdx.x;
    int i = blockIdx.x * 256 + t;
    int v = (i < NN) ? deg[i] : 0;
    __shared__ int s[256];
    s[t] = v;
    __syncthreads();
    for (int off = 1; off < 256; off <<= 1) {
        int x = (t >= off) ? s[t - off] : 0;
        __syncthreads();
        s[t] += x;
        __syncthreads();
    }
    if (i < NN) rptr[i] = s[t] - v;
    if (t == 255) bsum[blockIdx.x] = s[255];
}

__global__ void k_scan3(int* __restrict__ rptr, const int* __restrict__ bsum) {
    int t = threadIdx.x;
    int v = (t < NB_SCAN && t < blockIdx.x) ? bsum[t] : 0;
#pragma unroll
    for (int off = 32; off > 0; off >>= 1) v += __shfl_xor(v, off);
    __shared__ int wsum[4];
    if ((t & 63) == 0) wsum[t >> 6] = v;
    __syncthreads();
    int pre = wsum[0] + wsum[1] + wsum[2] + wsum[3];
    int i = blockIdx.x * 256 + t;
    if (i < NN) rptr[i] += pre;
}

__global__ void k_fill(const int* __restrict__ src, const int* __restrict__ dst,
                       const int* __restrict__ rptr, int* __restrict__ fill,
                       int* __restrict__ esrc) {
    int e = blockIdx.x * blockDim.x + threadIdx.x;
    if (e >= NE) return;
    int d = dst[e];
    int pos = rptr[d] + atomicAdd(&fill[d], 1);
    esrc[pos] = src[e];
}

// ---------------- GAT aggregation: 4-way edge-parallel ushort4 gather ----------------
// 128 threads: sub = t>>5 (edge slot), fq = t&31 (feature quad). exp once per edge.
__global__ __launch_bounds__(128) void k_gat_agg(
    const int* __restrict__ rptr, const int* __restrict__ deg,
    const int* __restrict__ esrc, const float* __restrict__ hs,
    const float* __restrict__ hd, const bf16_t* __restrict__ h,
    const float* __restrict__ bg, bf16_t* __restrict__ h1) {
    int row = blockIdx.x;
    int t = threadIdx.x;
    int lane = t & 63, wid = t >> 6;
    int sub = t >> 5;            // 0..3
    int fq = t & 31;             // feats fq*4..+3
    int start = rptr[row];
    int dn = deg[row];
    int end = start + dn;
    float hdr = hd[row];
    float wself = __expf(leaky(hs[row] + hdr));

    __shared__ float ws[128];
    __shared__ int es[128];      // pre-scaled byte offsets (src*256)
    __shared__ float red[2];
    __shared__ __align__(16) float xr[32][4];

    float a0 = 0.f, a1 = 0.f, a2 = 0.f, a3 = 0.f;
    if (sub == 0) {
        ushort4 hv = *(const ushort4*)(h + (size_t)row * HID + fq * 4);
        a0 = wself * bf2f(hv.x); a1 = wself * bf2f(hv.y);
        a2 = wself * bf2f(hv.z); a3 = wself * bf2f(hv.w);
    }
    float denL = 0.f;
    for (int c = start; c < end; c += 128) {
        int cl = min(128, end - c);
        __syncthreads();
        float w = 0.f;
        if (t < cl) {
            int sn = esrc[c + t];
            es[t] = sn << 8;     // byte offset: sn * HID * 2
            w = __expf(leaky(hs[sn] + hdr));
            ws[t] = w;
        }
        denL += w;
        __syncthreads();
        for (int j = sub; j < cl; j += 4) {
            float wj = ws[j];
            const bf16_t* hr = (const bf16_t*)((const char*)h + (size_t)(unsigned)es[j]) + fq * 4;
            ushort4 hv = *(const ushort4*)hr;
            a0 = fmaf(wj, bf2f(hv.x), a0);
            a1 = fmaf(wj, bf2f(hv.y), a1);
            a2 = fmaf(wj, bf2f(hv.z), a2);
            a3 = fmaf(wj, bf2f(hv.w), a3);
        }
    }
    // block-sum of denL
#pragma unroll
    for (int off = 32; off > 0; off >>= 1) denL += __shfl_xor(denL, off);
    if (lane == 0) red[wid] = denL;
    // fold edge-subslots: {0,1} and {2,3} within each wave
    a0 += __shfl_xor(a0, 32); a1 += __shfl_xor(a1, 32);
    a2 += __shfl_xor(a2, 32); a3 += __shfl_xor(a3, 32);
    if (wid == 1 && lane < 32) {
        xr[lane][0] = a0; xr[lane][1] = a1; xr[lane][2] = a2; xr[lane][3] = a3;
    }
    __syncthreads();
    if (wid == 0 && lane < 32) {
        float den = wself + red[0] + red[1];
        float inv = 1.f / den;
        float4 xv = *(const float4*)xr[lane];
        float4 b4 = *(const float4*)(bg + fq * 4);
        float v0 = (a0 + xv.x) * inv + b4.x;
        float v1 = (a1 + xv.y) * inv + b4.y;
        float v2 = (a2 + xv.z) * inv + b4.z;
        float v3 = (a3 + xv.w) * inv + b4.w;
        ushort4 o;
        o.x = f2bf(v0 > 0.f ? v0 : 0.f);
        o.y = f2bf(v1 > 0.f ? v1 : 0.f);
        o.z = f2bf(v2 > 0.f ? v2 : 0.f);
        o.w = f2bf(v3 > 0.f ? v3 : 0.f);
        *(ushort4*)(h1 + (size_t)row * HID + fq * 4) = o;
    }
}

// ---------------- SAGE mean gather: 2 nodes/block (1 wave each), 2-way edge slots ----------------
__global__ __launch_bounds__(128) void k_sage_gather(
    const int* __restrict__ rptr, const int* __restrict__ deg,
    const int* __restrict__ esrc, const bf16_t* __restrict__ h1,
    bf16_t* __restrict__ mean) {
    int t = threadIdx.x;
    int wid = t >> 6;
    int row = blockIdx.x * 2 + wid;
    if (row >= NN) return;
    int lane = t & 63;
    int sub = (t >> 5) & 1;      // 0..1
    int fq = t & 31;
    int start = rptr[row];
    int dn = deg[row];
    int end = start + dn;
    float a0 = 0.f, a1 = 0.f, a2 = 0.f, a3 = 0.f;
    int e = start + sub;
    for (; e + 2 < end; e += 4) {      // unroll 2 per subslot
        const bf16_t* r0 = h1 + (size_t)esrc[e] * HID + fq * 4;
        const bf16_t* r1 = h1 + (size_t)esrc[e + 2] * HID + fq * 4;
        ushort4 u0 = *(const ushort4*)r0;
        ushort4 u1 = *(const ushort4*)r1;
        a0 += bf2f(u0.x) + bf2f(u1.x);
        a1 += bf2f(u0.y) + bf2f(u1.y);
        a2 += bf2f(u0.z) + bf2f(u1.z);
        a3 += bf2f(u0.w) + bf2f(u1.w);
    }
    if (e < end) {
        ushort4 u0 = *(const ushort4*)(h1 + (size_t)esrc[e] * HID + fq * 4);
        a0 += bf2f(u0.x); a1 += bf2f(u0.y); a2 += bf2f(u0.z); a3 += bf2f(u0.w);
    }
    a0 += __shfl_xor(a0, 32); a1 += __shfl_xor(a1, 32);
    a2 += __shfl_xor(a2, 32); a3 += __shfl_xor(a3, 32);
    if (lane < 32) {
        float inv = 1.f / (float)(dn > 0 ? dn : 1);
        ushort4 o;
        o.x = f2bf(a0 * inv); o.y = f2bf(a1 * inv);
        o.z = f2bf(a2 * inv); o.w = f2bf(a3 * inv);
        *(ushort4*)(mean + (size_t)row * HID + fq * 4) = o;
    }
}

// ---------------- Dense via MFMA: out = sigmoid(relu([mean|h1] @ [Wl;Wr] + bl) @ Wout + bout) ----
__global__ __launch_bounds__(256) void k_dense_mfma(
    const bf16_t* __restrict__ mean, const bf16_t* __restrict__ h1,
    const bf16_t* __restrict__ Bp, const float* __restrict__ bl,
    const float* __restrict__ Wout, const float* __restrict__ bout,
    float* __restrict__ out) {
    int tid = threadIdx.x;
    int lane = tid & 63;
    int wv = tid >> 6;
    int node0 = blockIdx.x * DN_NODES + wv * 16;
    int arow = lane & 15;
    int kg = lane >> 4;
    int gn = node0 + arow;
    if (gn >= NN) gn = NN - 1;
    const bf16_t* mrow = mean + (size_t)gn * HID;
    const bf16_t* srow = h1 + (size_t)gn * HID;
    const bf16x8* bp = (const bf16x8*)Bp;

    f32x4 acc[8];
#pragma unroll
    for (int n = 0; n < 8; ++n) acc[n] = (f32x4){0.f, 0.f, 0.f, 0.f};

#pragma unroll
    for (int kb = 0; kb < 8; ++kb) {
        int k0 = kb * 32 + kg * 8;
        bf16x8 a = (kb < 4) ? *(const bf16x8*)(mrow + k0)
                            : *(const bf16x8*)(srow + (k0 - HID));
#pragma unroll
        for (int n = 0; n < 8; ++n) {
            bf16x8 b = bp[((n * 8 + kb) << 6) + lane];
            acc[n] = __builtin_amdgcn_mfma_f32_16x16x32_bf16(a, b, acc[n], 0, 0, 0);
        }
    }

    float pr[4] = {0.f, 0.f, 0.f, 0.f};
#pragma unroll
    for (int n = 0; n < 8; ++n) {
        int f = n * 16 + arow;
        float b = bl[f];
        float wo = Wout[f];
#pragma unroll
        for (int r = 0; r < 4; ++r) {
            float v = fmaxf(acc[n][r] + b, 0.f);
            pr[r] = fmaf(v, wo, pr[r]);
        }
    }
#pragma unroll
    for (int off = 8; off > 0; off >>= 1) {
#pragma unroll
        for (int r = 0; r < 4; ++r) pr[r] += __shfl_xor(pr[r], off);
    }
    if (arow == 0) {
        float bo = bout[0];
#pragma unroll
        for (int r = 0; r < 4; ++r) {
            int gno = node0 + kg * 4 + r;
            if (gno < NN) out[gno] = 1.f / (1.f + __expf(-(pr[r] + bo)));
        }
    }
}

extern "C" void kernel_launch(void* const* d_in, const int* in_sizes, int n_in,
                              void* d_out, int out_size, void* d_ws, size_t ws_size,
                              hipStream_t stream) {
    const float* x    = (const float*)d_in[0];
    const int*   ei   = (const int*)d_in[1];
    const float* Wg   = (const float*)d_in[2];
    const float* a_s  = (const float*)d_in[3];
    const float* a_d  = (const float*)d_in[4];
    const float* bg   = (const float*)d_in[5];
    const float* Wl   = (const float*)d_in[6];
    const float* bl   = (const float*)d_in[7];
    const float* Wr   = (const float*)d_in[8];
    const float* Wout = (const float*)d_in[9];
    const float* bout = (const float*)d_in[10];
    float* out = (float*)d_out;

    const int* src = ei;
    const int* dst = ei + NE;

    bf16_t* h    = (bf16_t*)d_ws;                  // NN*HID bf16
    bf16_t* h1   = h + (size_t)NN * HID;           // NN*HID bf16
    bf16_t* mean = h1 + (size_t)NN * HID;          // NN*HID bf16
    bf16_t* Bp   = mean + (size_t)NN * HID;        // 64 KB packed weights
    float* hs = (float*)(Bp + 8 * 8 * 64 * 8);     // NN
    float* hd = hs + NN;                           // NN
    int* deg  = (int*)(hd + NN);                   // NN  (zeroed)
    int* fill = deg + NN;                          // NN  (zeroed)
    int* rptr = fill + NN;                         // NN
    int* bsum = rptr + NN;                         // NB_SCAN
    int* esrc = bsum + NB_SCAN;                    // NE

    hipMemsetAsync(deg, 0, (size_t)2 * NN * sizeof(int), stream);

    k_pack_w<<<16, 256, 0, stream>>>(Wl, Wr, Bp);
    k_gat_in<<<NB_GIN, 256, 0, stream>>>(x, Wg, a_s, a_d, h, hs, hd);

    k_hist<<<(NE + 255) / 256, 256, 0, stream>>>(dst, deg);
    k_scan1<<<NB_SCAN, 256, 0, stream>>>(deg, rptr, bsum);
    k_scan3<<<NB_SCAN, 256, 0, stream>>>(rptr, bsum);
    k_fill<<<(NE + 255) / 256, 256, 0, stream>>>(src, dst, rptr, fill, esrc);

    k_gat_agg<<<NN, 128, 0, stream>>>(rptr, deg, esrc, hs, hd, h, bg, h1);
    k_sage_gather<<<(NN + 1) / 2, 128, 0, stream>>>(rptr, deg, esrc, h1, mean);
    k_dense_mfma<<<NB_DENSE, 256, 0, stream>>>(mean, h1, Bp, bl, Wout, bout, out);
}

// Round 9
// 170.713 us; speedup vs baseline: 1.8305x; 1.1586x over previous
//
#include <hip/hip_runtime.h>

#define NN 50000
#define NE 600000
#define F_IN 57
#define HID 128
#define NEG 0.2f
#define NB_SCAN ((NN + 255) / 256)

#define GIN_NODES 64
#define NB_GIN ((NN + GIN_NODES - 1) / GIN_NODES)
#define XST 68

#define DN_NODES 64            // nodes per MFMA dense block (4 waves x 16)
#define NB_DENSE ((NN + DN_NODES - 1) / DN_NODES)

typedef unsigned short bf16_t;
typedef __attribute__((ext_vector_type(8))) short bf16x8;
typedef __attribute__((ext_vector_type(4))) float f32x4;

__device__ __forceinline__ float leaky(float v) { return v >= 0.f ? v : NEG * v; }
__device__ __forceinline__ float bf2f(bf16_t u) { return __uint_as_float(((unsigned)u) << 16); }
__device__ __forceinline__ bf16_t f2bf(float f) {
    unsigned u = __float_as_uint(f);
    return (bf16_t)((u + 0x7FFFu + ((u >> 16) & 1u)) >> 16);   // RNE
}

// ---------------- K1: tiled  h = x @ W_gat (bf16 out) ; hs = h.a_src ; hd = h.a_dst ----------------
__global__ __launch_bounds__(256) void k_gat_in(
    const float* __restrict__ x, const float* __restrict__ Wg,
    const float* __restrict__ a_s, const float* __restrict__ a_d,
    bf16_t* __restrict__ h, float* __restrict__ hs, float* __restrict__ hd) {
    __shared__ float WgS[F_IN * HID];
    __shared__ float xsT[F_IN][XST];
    int tid = threadIdx.x;
    int node0 = blockIdx.x * GIN_NODES;
    {
        const float4* g = (const float4*)Wg;
        float4* s = (float4*)WgS;
        for (int i = tid; i < F_IN * HID / 4; i += 256) s[i] = g[i];
    }
    for (int i = tid; i < GIN_NODES * F_IN; i += 256) {
        int n = i / F_IN;
        int k = i - n * F_IN;
        int gn = node0 + n;
        if (gn >= NN) gn = NN - 1;
        xsT[k][n] = x[gn * F_IN + k];
    }
    __syncthreads();

    int fq = tid & 31, nq = tid >> 5;
    int f0 = fq * 4, nb = nq * 8;
    float acc[8][4];
#pragma unroll
    for (int i = 0; i < 8; ++i)
#pragma unroll
        for (int j = 0; j < 4; ++j) acc[i][j] = 0.f;

    for (int k = 0; k < F_IN; ++k) {
        float4 w = *(const float4*)&WgS[k * HID + f0];
        float4 xa = *(const float4*)&xsT[k][nb];
        float4 xb = *(const float4*)&xsT[k][nb + 4];
        float xv[8] = {xa.x, xa.y, xa.z, xa.w, xb.x, xb.y, xb.z, xb.w};
        float wv[4] = {w.x, w.y, w.z, w.w};
#pragma unroll
        for (int i = 0; i < 8; ++i)
#pragma unroll
            for (int j = 0; j < 4; ++j)
                acc[i][j] = fmaf(xv[i], wv[j], acc[i][j]);
    }

    float4 as4 = *(const float4*)(a_s + f0);
    float4 ad4 = *(const float4*)(a_d + f0);
    float ps[8], pd[8];
#pragma unroll
    for (int i = 0; i < 8; ++i) {
        int gn = node0 + nb + i;
        if (gn < NN) {
            ushort4 hv;
            hv.x = f2bf(acc[i][0]); hv.y = f2bf(acc[i][1]);
            hv.z = f2bf(acc[i][2]); hv.w = f2bf(acc[i][3]);
            *(ushort4*)(h + (size_t)gn * HID + f0) = hv;
        }
        ps[i] = acc[i][0] * as4.x + acc[i][1] * as4.y + acc[i][2] * as4.z + acc[i][3] * as4.w;
        pd[i] = acc[i][0] * ad4.x + acc[i][1] * ad4.y + acc[i][2] * ad4.z + acc[i][3] * ad4.w;
    }
#pragma unroll
    for (int off = 16; off > 0; off >>= 1) {
#pragma unroll
        for (int i = 0; i < 8; ++i) {
            ps[i] += __shfl_xor(ps[i], off);
            pd[i] += __shfl_xor(pd[i], off);
        }
    }
    if (fq == 0) {
#pragma unroll
        for (int i = 0; i < 8; ++i) {
            int gn = node0 + nb + i;
            if (gn < NN) { hs[gn] = ps[i]; hd[gn] = pd[i]; }
        }
    }
}

// ---------------- weight pack: [Wl;Wr] f32 -> bf16 MFMA B-fragment order ----------------
__global__ __launch_bounds__(256) void k_pack_w(
    const float* __restrict__ Wl, const float* __restrict__ Wr, bf16_t* __restrict__ Bp) {
    int idx = blockIdx.x * 256 + threadIdx.x;
    if (idx >= 8 * 8 * 64) return;
    int lane = idx & 63;
    int kb = (idx >> 6) & 7;
    int nt = idx >> 9;
    int col = nt * 16 + (lane & 15);
    int kbase = kb * 32 + (lane >> 4) * 8;
    bf16_t v[8];
#pragma unroll
    for (int j = 0; j < 8; ++j) {
        int k = kbase + j;
        float w = (k < HID) ? Wl[k * HID + col] : Wr[(k - HID) * HID + col];
        v[j] = f2bf(w);
    }
    ushort4* o = (ushort4*)(Bp + (size_t)idx * 8);
    ushort4 lo, hi;
    lo.x = v[0]; lo.y = v[1]; lo.z = v[2]; lo.w = v[3];
    hi.x = v[4]; hi.y = v[5]; hi.z = v[6]; hi.w = v[7];
    o[0] = lo; o[1] = hi;
}

// ---------------- CSR build ----------------
__global__ void k_hist(const int* __restrict__ dst, int* __restrict__ deg) {
    int e = blockIdx.x * blockDim.x + threadIdx.x;
    if (e < NE) atomicAdd(&deg[dst[e]], 1);
}

__global__ void k_scan1(const int* __restrict__ deg, int* __restrict__ rptr, int* __restrict__ bsum) {
    int t = threadIdx.x;
    int i = blockIdx.x * 256 + t;
    int v = (i < NN) ? deg[i] : 0;
    __shared__ int s[256];
    s[t] = v;
    __syncthreads();
    for (int off = 1; off < 256; off <<= 1) {
        int x = (t >= off) ? s[t - off] : 0;
        __syncthreads();
        s[t] += x;
        __syncthreads();
    }
    if (i < NN) rptr[i] = s[t] - v;
    if (t == 255) bsum[blockIdx.x] = s[255];
}

__global__ void k_scan3(int* __restrict__ rptr, const int* __restrict__ bsum) {
    int t = threadIdx.x;
    int v = (t < NB_SCAN && t < blockIdx.x) ? bsum[t] : 0;
#pragma unroll
    for (int off = 32; off > 0; off >>= 1) v += __shfl_xor(v, off);
    __shared__ int wsum[4];
    if ((t & 63) == 0) wsum[t >> 6] = v;
    __syncthreads();
    int pre = wsum[0] + wsum[1] + wsum[2] + wsum[3];
    int i = blockIdx.x * 256 + t;
    if (i < NN) rptr[i] += pre;
}

__global__ void k_fill(const int* __restrict__ src, const int* __restrict__ dst,
                       const int* __restrict__ rptr, int* __restrict__ fill,
                       int* __restrict__ esrc) {
    int e = blockIdx.x * blockDim.x + threadIdx.x;
    if (e >= NE) return;
    int d = dst[e];
    int pos = rptr[d] + atomicAdd(&fill[d], 1);
    esrc[pos] = src[e];
}

// ---------------- GAT aggregation: wave-per-node, barrier-free ----------------
// 256 threads = 4 waves = 4 nodes. lane: slot = lane>>4 (edge), f8 = lane&15 (feat oct).
// Per 4-edge group: bcast esrc load + hs gather + exp (dup x16) + b128 row load.
__global__ __launch_bounds__(256) void k_gat_agg(
    const int* __restrict__ rptr, const int* __restrict__ deg,
    const int* __restrict__ esrc, const float* __restrict__ hs,
    const float* __restrict__ hd, const bf16_t* __restrict__ h,
    const float* __restrict__ bg, bf16_t* __restrict__ h1) {
    int tid = threadIdx.x;
    int row = blockIdx.x * 4 + (tid >> 6);
    if (row >= NN) return;
    int lane = tid & 63;
    int slot = lane >> 4;
    int f8 = lane & 15;

    int start = rptr[row];
    int dn = deg[row];
    int end = start + dn;
    float hdr = hd[row];
    float wself = __expf(leaky(hs[row] + hdr));

    float a[8];
#pragma unroll
    for (int j = 0; j < 8; ++j) a[j] = 0.f;
    float denL = 0.f;

    if (slot == 0) {
        bf16x8 r = *(const bf16x8*)(h + (size_t)row * HID + f8 * 8);
#pragma unroll
        for (int j = 0; j < 8; ++j) a[j] = wself * bf2f((bf16_t)r[j]);
    }

    int e = start;
    for (; e + 8 <= end; e += 8) {          // 2 groups in flight
        int s0 = esrc[e + slot];
        int s1 = esrc[e + 4 + slot];
        float w0 = __expf(leaky(hs[s0] + hdr));
        float w1 = __expf(leaky(hs[s1] + hdr));
        bf16x8 r0 = *(const bf16x8*)(h + (size_t)s0 * HID + f8 * 8);
        bf16x8 r1 = *(const bf16x8*)(h + (size_t)s1 * HID + f8 * 8);
        denL += w0 + w1;
#pragma unroll
        for (int j = 0; j < 8; ++j) {
            a[j] = fmaf(w0, bf2f((bf16_t)r0[j]), a[j]);
            a[j] = fmaf(w1, bf2f((bf16_t)r1[j]), a[j]);
        }
    }
    for (; e < end; e += 4) {               // predicated tail
        int i = e + slot;
        bool act = i < end;
        int sn = esrc[act ? i : end - 1];
        float w = act ? __expf(leaky(hs[sn] + hdr)) : 0.f;
        bf16x8 r = *(const bf16x8*)(h + (size_t)sn * HID + f8 * 8);
        denL += w;
#pragma unroll
        for (int j = 0; j < 8; ++j) a[j] = fmaf(w, bf2f((bf16_t)r[j]), a[j]);
    }

    // fold 4 edge-slots (denL identical within a slot; a[] differ per slot)
#pragma unroll
    for (int j = 0; j < 8; ++j) {
        a[j] += __shfl_xor(a[j], 16);
        a[j] += __shfl_xor(a[j], 32);
    }
    denL += __shfl_xor(denL, 16);
    denL += __shfl_xor(denL, 32);
    float inv = 1.f / (wself + denL);

    if (lane < 16) {
        float4 b0 = *(const float4*)(bg + lane * 8);
        float4 b1 = *(const float4*)(bg + lane * 8 + 4);
        float bb[8] = {b0.x, b0.y, b0.z, b0.w, b1.x, b1.y, b1.z, b1.w};
        bf16x8 o;
#pragma unroll
        for (int j = 0; j < 8; ++j) {
            float v = a[j] * inv + bb[j];
            o[j] = (short)f2bf(v > 0.f ? v : 0.f);
        }
        *(bf16x8*)(h1 + (size_t)row * HID + lane * 8) = o;
    }
}

// ---------------- SAGE mean gather: wave-per-node, barrier-free ----------------
__global__ __launch_bounds__(256) void k_sage_gather(
    const int* __restrict__ rptr, const int* __restrict__ deg,
    const int* __restrict__ esrc, const bf16_t* __restrict__ h1,
    bf16_t* __restrict__ mean) {
    int tid = threadIdx.x;
    int row = blockIdx.x * 4 + (tid >> 6);
    if (row >= NN) return;
    int lane = tid & 63;
    int slot = lane >> 4;
    int f8 = lane & 15;

    int start = rptr[row];
    int dn = deg[row];
    int end = start + dn;

    float a[8];
#pragma unroll
    for (int j = 0; j < 8; ++j) a[j] = 0.f;

    int e = start;
    for (; e + 8 <= end; e += 8) {
        int s0 = esrc[e + slot];
        int s1 = esrc[e + 4 + slot];
        bf16x8 r0 = *(const bf16x8*)(h1 + (size_t)s0 * HID + f8 * 8);
        bf16x8 r1 = *(const bf16x8*)(h1 + (size_t)s1 * HID + f8 * 8);
#pragma unroll
        for (int j = 0; j < 8; ++j)
            a[j] += bf2f((bf16_t)r0[j]) + bf2f((bf16_t)r1[j]);
    }
    for (; e < end; e += 4) {
        int i = e + slot;
        bool act = i < end;
        int sn = esrc[act ? i : end - 1];
        bf16x8 r = *(const bf16x8*)(h1 + (size_t)sn * HID + f8 * 8);
        float w = act ? 1.f : 0.f;
#pragma unroll
        for (int j = 0; j < 8; ++j) a[j] = fmaf(w, bf2f((bf16_t)r[j]), a[j]);
    }

#pragma unroll
    for (int j = 0; j < 8; ++j) {
        a[j] += __shfl_xor(a[j], 16);
        a[j] += __shfl_xor(a[j], 32);
    }
    if (lane < 16) {
        float inv = 1.f / (float)(dn > 0 ? dn : 1);
        bf16x8 o;
#pragma unroll
        for (int j = 0; j < 8; ++j) o[j] = (short)f2bf(a[j] * inv);
        *(bf16x8*)(mean + (size_t)row * HID + lane * 8) = o;
    }
}

// ---------------- Dense via MFMA: out = sigmoid(relu([mean|h1] @ [Wl;Wr] + bl) @ Wout + bout) ----
__global__ __launch_bounds__(256) void k_dense_mfma(
    const bf16_t* __restrict__ mean, const bf16_t* __restrict__ h1,
    const bf16_t* __restrict__ Bp, const float* __restrict__ bl,
    const float* __restrict__ Wout, const float* __restrict__ bout,
    float* __restrict__ out) {
    int tid = threadIdx.x;
    int lane = tid & 63;
    int wv = tid >> 6;
    int node0 = blockIdx.x * DN_NODES + wv * 16;
    int arow = lane & 15;
    int kg = lane >> 4;
    int gn = node0 + arow;
    if (gn >= NN) gn = NN - 1;
    const bf16_t* mrow = mean + (size_t)gn * HID;
    const bf16_t* srow = h1 + (size_t)gn * HID;
    const bf16x8* bp = (const bf16x8*)Bp;

    f32x4 acc[8];
#pragma unroll
    for (int n = 0; n < 8; ++n) acc[n] = (f32x4){0.f, 0.f, 0.f, 0.f};

#pragma unroll
    for (int kb = 0; kb < 8; ++kb) {
        int k0 = kb * 32 + kg * 8;
        bf16x8 a = (kb < 4) ? *(const bf16x8*)(mrow + k0)
                            : *(const bf16x8*)(srow + (k0 - HID));
#pragma unroll
        for (int n = 0; n < 8; ++n) {
            bf16x8 b = bp[((n * 8 + kb) << 6) + lane];
            acc[n] = __builtin_amdgcn_mfma_f32_16x16x32_bf16(a, b, acc[n], 0, 0, 0);
        }
    }

    float pr[4] = {0.f, 0.f, 0.f, 0.f};
#pragma unroll
    for (int n = 0; n < 8; ++n) {
        int f = n * 16 + arow;
        float b = bl[f];
        float wo = Wout[f];
#pragma unroll
        for (int r = 0; r < 4; ++r) {
            float v = fmaxf(acc[n][r] + b, 0.f);
            pr[r] = fmaf(v, wo, pr[r]);
        }
    }
#pragma unroll
    for (int off = 8; off > 0; off >>= 1) {
#pragma unroll
        for (int r = 0; r < 4; ++r) pr[r] += __shfl_xor(pr[r], off);
    }
    if (arow == 0) {
        float bo = bout[0];
#pragma unroll
        for (int r = 0; r < 4; ++r) {
            int gno = node0 + kg * 4 + r;
            if (gno < NN) out[gno] = 1.f / (1.f + __expf(-(pr[r] + bo)));
        }
    }
}

extern "C" void kernel_launch(void* const* d_in, const int* in_sizes, int n_in,
                              void* d_out, int out_size, void* d_ws, size_t ws_size,
                              hipStream_t stream) {
    const float* x    = (const float*)d_in[0];
    const int*   ei   = (const int*)d_in[1];
    const float* Wg   = (const float*)d_in[2];
    const float* a_s  = (const float*)d_in[3];
    const float* a_d  = (const float*)d_in[4];
    const float* bg   = (const float*)d_in[5];
    const float* Wl   = (const float*)d_in[6];
    const float* bl   = (const float*)d_in[7];
    const float* Wr   = (const float*)d_in[8];
    const float* Wout = (const float*)d_in[9];
    const float* bout = (const float*)d_in[10];
    float* out = (float*)d_out;

    const int* src = ei;
    const int* dst = ei + NE;

    bf16_t* h    = (bf16_t*)d_ws;                  // NN*HID bf16
    bf16_t* h1   = h + (size_t)NN * HID;           // NN*HID bf16
    bf16_t* mean = h1 + (size_t)NN * HID;          // NN*HID bf16
    bf16_t* Bp   = mean + (size_t)NN * HID;        // 64 KB packed weights
    float* hs = (float*)(Bp + 8 * 8 * 64 * 8);     // NN
    float* hd = hs + NN;                           // NN
    int* deg  = (int*)(hd + NN);                   // NN  (zeroed)
    int* fill = deg + NN;                          // NN  (zeroed)
    int* rptr = fill + NN;                         // NN
    int* bsum = rptr + NN;                         // NB_SCAN
    int* esrc = bsum + NB_SCAN;                    // NE

    hipMemsetAsync(deg, 0, (size_t)2 * NN * sizeof(int), stream);

    k_pack_w<<<16, 256, 0, stream>>>(Wl, Wr, Bp);
    k_gat_in<<<NB_GIN, 256, 0, stream>>>(x, Wg, a_s, a_d, h, hs, hd);

    k_hist<<<(NE + 255) / 256, 256, 0, stream>>>(dst, deg);
    k_scan1<<<NB_SCAN, 256, 0, stream>>>(deg, rptr, bsum);
    k_scan3<<<NB_SCAN, 256, 0, stream>>>(rptr, bsum);
    k_fill<<<(NE + 255) / 256, 256, 0, stream>>>(src, dst, rptr, fill, esrc);

    k_gat_agg<<<(NN + 3) / 4, 256, 0, stream>>>(rptr, deg, esrc, hs, hd, h, bg, h1);
    k_sage_gather<<<(NN + 3) / 4, 256, 0, stream>>>(rptr, deg, esrc, h1, mean);
    k_dense_mfma<<<NB_DENSE, 256, 0, stream>>>(mean, h1, Bp, bl, Wout, bout, out);
}